// Round 8
// baseline (779.881 us; speedup 1.0000x reference)
//
#include <hip/hip_runtime.h>

// ---------------------------------------------------------------------------
// FCGRU (fp32 globals; bf16 in MFMA frags):
//   input(1024,128,32) -> FC(32->256) -> FC(256->512) -> GRU(512) over T=128
//   -> relu -> FC(512->256)+relu -> per-cultivar head (256->16)
// Input-side linears collapse: gx = input @ (W_ih@W2@W1).T + b_eff  (K=32 MFMA).
// Persistent GRU: 512 blocks = 64 groups (16 batches) x 8 col-blocks (64 cols),
// 2 blocks/CU (launch_bounds(256,2), VGPR<=256 -> 2 waves/SIMD). Co-resident
// blocks (b, b+256) are in groups g and g+32: INDEPENDENT barriers, so one
// block computes while the other waits. Cross-block h via sc1 (relaxed agent
// atomics, MALL-coherent). W_hh B-frags register-resident (48 short8/wave).
// 16.5KB LDS h slab, coalesced sc1 staging, 8-flag barrier (no RMW).
// ---------------------------------------------------------------------------

#define T_STEPS 128
#define PITCH   516             // u16 row pitch in LDS: b64 frag reads ~conflict-free
#define SLAB_ROWS 16

typedef __attribute__((ext_vector_type(8))) short short8;
typedef __attribute__((ext_vector_type(4))) float f32x4;
typedef __attribute__((ext_vector_type(4))) float float4v;
typedef unsigned short u16;
typedef unsigned long long u64;

static __device__ __forceinline__ u16 f2bf(float f) {
    unsigned int u = __builtin_bit_cast(unsigned int, f);
    u += 0x7FFFu + ((u >> 16) & 1u);          // round-to-nearest-even
    return (u16)(u >> 16);
}
static __device__ __forceinline__ f32x4 mfma16(short8 a, short8 b, f32x4 c) {
    return __builtin_amdgcn_mfma_f32_16x16x32_bf16(a, b, c, 0, 0, 0);
}
// device-coherent (MALL) accesses: relaxed agent atomics -> plain sc1 ld/st
static __device__ __forceinline__ void st_h16(u16* p, short8 v) {
    struct W { u64 a, b; } w = __builtin_bit_cast(W, v);
    u64* q = (u64*)p;
    __hip_atomic_store(q + 0, w.a, __ATOMIC_RELAXED, __HIP_MEMORY_SCOPE_AGENT);
    __hip_atomic_store(q + 1, w.b, __ATOMIC_RELAXED, __HIP_MEMORY_SCOPE_AGENT);
}
static __device__ __forceinline__ u64 ld_sc1_u64(const u16* p) {
    return __hip_atomic_load((const u64*)p, __ATOMIC_RELAXED, __HIP_MEMORY_SCOPE_AGENT);
}
// 16B LDS fragment read as two b64 (8B-aligned)
static __device__ __forceinline__ short8 lds8(const u16* p) {
    u64 lo = *(const u64*)p;
    u64 hi = *(const u64*)(p + 4);
    struct W { u64 a, b; } w{lo, hi};
    return __builtin_bit_cast(short8, w);
}

// ---------------- workspace layout (bytes) ----------------
#define WS_HBUF0 0           // 1024*512*2 bf16 h buffer 0
#define WS_HBUF1 1048576     // 1024*512*2 bf16 h buffer 1
#define WS_W21   2097152     // 512*32*4 fp32 W2@W1
#define WS_B21   2162688     // 512*4
#define WS_WEFF  2164736     // 1536*32*2 bf16 W_ih@W2@W1
#define WS_BEFF  2263040     // 1536*4
#define WS_FLAGS 2269184     // 64 groups x 8 slots x 4B = 2048

// ---------------- prologue 0: W21 = W2@W1 (fp32); b21 = W2@b1 + b2; zero flags
__global__ void k_prep0(const float* __restrict__ W1, const float* __restrict__ b1,
                        const float* __restrict__ W2, const float* __restrict__ b2,
                        float* __restrict__ W21, float* __restrict__ b21,
                        unsigned* __restrict__ flags) {
    if (blockIdx.x == 0) {
        __hip_atomic_store(&flags[threadIdx.x], 0u, __ATOMIC_RELAXED, __HIP_MEMORY_SCOPE_AGENT);
        __hip_atomic_store(&flags[256 + threadIdx.x], 0u, __ATOMIC_RELAXED, __HIP_MEMORY_SCOPE_AGENT);
    }
    int gid = blockIdx.x * 256 + threadIdx.x;   // 64 blocks: 512*32 outputs
    int k = gid >> 5, d = gid & 31;
    float acc = 0.f;
    for (int j = 0; j < 256; ++j)
        acc += W2[k * 256 + j] * W1[j * 32 + d];
    W21[k * 32 + d] = acc;
    if (d == 0) {
        float bb = b2[k];
        for (int j = 0; j < 256; ++j) bb += W2[k * 256 + j] * b1[j];
        b21[k] = bb;
    }
}

// ---------------- prologue 1: Weff = bf16(W_ih@W21); beff = W_ih@b21 + b_ih
__global__ void k_prep1(const float* __restrict__ W_ih, const float* __restrict__ b_ih,
                        const float* __restrict__ W21, const float* __restrict__ b21,
                        u16* __restrict__ Weff, float* __restrict__ beff) {
    int gid = blockIdx.x * 256 + threadIdx.x;   // 192 blocks: 1536*32 outputs
    int g = gid >> 5, d = gid & 31;
    float acc = 0.f;
    for (int k = 0; k < 512; ++k)
        acc += W_ih[g * 512 + k] * W21[k * 32 + d];
    Weff[g * 32 + d] = f2bf(acc);
    if (d == 0) {
        float bb = b_ih[g];
        for (int k = 0; k < 512; ++k) bb += W_ih[g * 512 + k] * b21[k];
        beff[g] = bb;
    }
}

// ---------------- flag barrier (no RMW) ----------------
static __device__ __forceinline__ void bar_arrive(unsigned* gflags, int slot, unsigned v) {
    __syncthreads();      // drains vmcnt(0): all waves' sc1 h-stores at MALL
    if (threadIdx.x == 0)
        __hip_atomic_store(&gflags[slot], v, __ATOMIC_RELAXED, __HIP_MEMORY_SCOPE_AGENT);
}
static __device__ __forceinline__ void bar_wait(const unsigned* gflags, unsigned v) {
    if (threadIdx.x < 64) {
        int idx = threadIdx.x & 7;               // 8 flags, one 32B span
        for (;;) {
            unsigned f = __hip_atomic_load(&gflags[idx], __ATOMIC_RELAXED, __HIP_MEMORY_SCOPE_AGENT);
            if (__ballot(f >= v) == ~0ull) break;
            __builtin_amdgcn_s_sleep(1);
        }
    }
    __syncthreads();
}

// ---------------- GRU persistent kernel ----------------
// grid 512 x 256, 2 blocks/CU. grp = (blk&31)|((blk>>8)<<5)  (64 groups x 16
// batches; co-resident pair (b,b+256) -> groups g,g+32: independent barriers).
// colg = (blk>>5)&7 (64 cols/block). wave w owns cols colg*64+w*16, one m-tile.
__launch_bounds__(256, 2)
__global__ void k_gru(const float* __restrict__ input, const float* __restrict__ hn,
                      const float* __restrict__ W_hh, const float* __restrict__ b_hh,
                      const u16* __restrict__ Weff, const float* __restrict__ beff,
                      u16* __restrict__ hbuf0, u16* __restrict__ hbuf1,
                      unsigned* __restrict__ flags, float* __restrict__ hn_out) {
    __shared__ __align__(16) u16 slab[SLAB_ROWS * PITCH];   // 16.5 KB h slab

    const int tid  = threadIdx.x;
    const int wave = tid >> 6, lane = tid & 63;
    const int col_l = lane & 15, quad = lane >> 4;
    const int blk = blockIdx.x;
    const int grp = (blk & 31) | ((blk >> 8) << 5);
    const int colg = (blk >> 5) & 7;
    const int grpbase = grp * 16;               // group's 16 batches
    const int cb = colg * 64 + wave * 16;       // wave's 16-col tile base
    unsigned* gflags = flags + grp * 8;

    // stage group's 16 rows of hn -> hbuf0 (bf16, sc1): only colg==0 blocks
    if (colg == 0) {
        #pragma unroll
        for (int r4 = 0; r4 < 4; ++r4) {
            int b = grpbase + wave * 4 + r4;
            const float* src = hn + (size_t)b * 512 + lane * 8;
            short8 v;
            #pragma unroll
            for (int e = 0; e < 8; ++e) v[e] = (short)f2bf(src[e]);
            st_h16(hbuf0 + (size_t)b * 512 + lane * 8, v);
        }
    }
    // register-resident W_hh B-frags: 3 gates x 16 kc (step-invariant)
    short8 whhf[3][16];
    #pragma unroll
    for (int g3 = 0; g3 < 3; ++g3) {
        const float* wrow = W_hh + (size_t)(g3 * 512 + cb + col_l) * 512;
        #pragma unroll
        for (int kc = 0; kc < 16; ++kc) {
            const float* p = wrow + kc * 32 + quad * 8;
            short8 v;
            #pragma unroll
            for (int e = 0; e < 8; ++e) v[e] = (short)f2bf(p[e]);
            whhf[g3][kc] = v;
        }
    }
    // register-resident W_eff B-frags (bf16) + per-column biases (fp32)
    short8 bwx[3];
    float bx[3], bhh[3];
    #pragma unroll
    for (int g3 = 0; g3 < 3; ++g3) {
        int nr = g3 * 512 + cb + col_l;
        bwx[g3] = *(const short8*)(Weff + nr * 32 + quad * 8);
        bx[g3]  = beff[nr];
        bhh[g3] = b_hh[nr];
    }
    // fp32 carried h-state: batch = grpbase + quad*4 + i, col = cb + col_l
    float hs[4];
    #pragma unroll
    for (int i = 0; i < 4; ++i)
        hs[i] = hn[(size_t)(grpbase + quad * 4 + i) * 512 + cb + col_l];

    bar_arrive(gflags, colg, 1u);                 // hn staging published

    u16* bufs[2] = { hbuf0, hbuf1 };
    #pragma unroll 1
    for (int t = 0; t < T_STEPS; ++t) {
        const u16* hsrc = bufs[t & 1];
        u16* hdst = bufs[(t + 1) & 1];

        // x load + gx seed (h-independent; overlaps the barrier wait)
        short8 ax;
        {
            const float* xp = input + (size_t)(grpbase + col_l) * 4096 + t * 32 + quad * 8;
            float4v a = *(const float4v*)xp;
            float4v b = *(const float4v*)(xp + 4);
            #pragma unroll
            for (int e = 0; e < 4; ++e) { ax[e] = (short)f2bf(a[e]); ax[4 + e] = (short)f2bf(b[e]); }
        }
        f32x4 z4 = { 0.f, 0.f, 0.f, 0.f };
        f32x4 ar  = mfma16(ax, bwx[0], z4);
        f32x4 az  = mfma16(ax, bwx[1], z4);
        f32x4 anx = mfma16(ax, bwx[2], z4);
        f32x4 anh = z4;

        bar_wait(gflags, (unsigned)(t + 1));      // h(t) visible group-wide

        // stage the 16-row slab coalesced (lane-contiguous sc1), rows rotated
        // by colg so the 8 blocks of a group don't hit identical MALL lines
        {
            u64 stg[8];
            #pragma unroll
            for (int r4 = 0; r4 < 4; ++r4) {
                int r = (wave * 4 + r4 + colg * 2) & 15;
                #pragma unroll
                for (int j = 0; j < 2; ++j)
                    stg[r4 * 2 + j] = ld_sc1_u64(hsrc + (size_t)(grpbase + r) * 512 + j * 256 + lane * 4);
            }
            #pragma unroll
            for (int r4 = 0; r4 < 4; ++r4) {
                int r = (wave * 4 + r4 + colg * 2) & 15;
                #pragma unroll
                for (int j = 0; j < 2; ++j)
                    *(u64*)&slab[r * PITCH + j * 256 + lane * 4] = stg[r4 * 2 + j];
            }
        }
        __syncthreads();                          // slab ready

        // gh: K=512, A from slab, B from registers
        const int arow = col_l * PITCH;
        #pragma unroll
        for (int kc = 0; kc < 16; ++kc) {
            short8 a = lds8(slab + arow + kc * 32 + quad * 8);
            ar  = mfma16(a, whhf[0][kc], ar);
            az  = mfma16(a, whhf[1][kc], az);
            anh = mfma16(a, whhf[2][kc], anh);
        }
        // gates + state update (fp32), sc1 bf16 h_new stores
        #pragma unroll
        for (int i = 0; i < 4; ++i) {
            float r = 1.f / (1.f + __expf(-(ar[i] + bx[0] + bhh[0])));
            float z = 1.f / (1.f + __expf(-(az[i] + bx[1] + bhh[1])));
            float np = anx[i] + bx[2] + r * (anh[i] + bhh[2]);
            float e  = __expf(-2.f * fabsf(np));
            float nn = __builtin_copysignf((1.f - e) / (1.f + e), np);
            float h  = (1.f - z) * nn + z * hs[i];
            hs[i] = h;
            int b = grpbase + quad * 4 + i;
            __hip_atomic_store(&hdst[(size_t)b * 512 + cb + col_l], f2bf(h),
                               __ATOMIC_RELAXED, __HIP_MEMORY_SCOPE_AGENT);
        }
        if (t < T_STEPS - 1)
            bar_arrive(gflags, colg, (unsigned)(t + 2));   // publish h(t+1)
    }
    // final hidden state -> d_out hn region (fp32)
    #pragma unroll
    for (int i = 0; i < 4; ++i)
        hn_out[(size_t)(grpbase + quad * 4 + i) * 512 + cb + col_l] = hs[i];
}

// ---------------- epilogue: out2 = relu(relu(h)@W3.T + b3); params = out2.Wh[cult] + bh
// hfin = bf16 final h (hbuf0: step 127 wrote buffer (127+1)&1 = 0).
// Cache-coherent here: kernel-launch boundary invalidates L1/L2.
__launch_bounds__(256)
__global__ void k_head(const u16* __restrict__ hfin, const float* __restrict__ W3,
                       const float* __restrict__ b3, const int* __restrict__ cult,
                       const float* __restrict__ Wh, const float* __restrict__ bh,
                       float* __restrict__ params) {
    __shared__ float out2[16][264];
    const int tid = threadIdx.x, wave = tid >> 6, lane = tid & 63;
    const int col_l = lane & 15, quad = lane >> 4;
    const int bbase = blockIdx.x * 16;            // 64 blocks x 16 batches

    f32x4 z4 = { 0.f, 0.f, 0.f, 0.f };
    f32x4 acc[4];
    #pragma unroll
    for (int nt = 0; nt < 4; ++nt) acc[nt] = z4;

    #pragma unroll
    for (int kc = 0; kc < 16; ++kc) {
        short8 a = *(const short8*)(hfin + (size_t)(bbase + col_l) * 512 + kc * 32 + quad * 8);
        #pragma unroll
        for (int e = 0; e < 8; ++e) {             // relu on packed bf16 (sign test)
            u16 v = (u16)a[e];
            a[e] = (short)((v & 0x8000u) ? 0 : v);
        }
        #pragma unroll
        for (int nt = 0; nt < 4; ++nt) {
            int nrow = wave * 64 + nt * 16 + col_l;
            const float* wr = W3 + (size_t)nrow * 512 + kc * 32 + quad * 8;
            short8 b;
            #pragma unroll
            for (int e = 0; e < 8; ++e) b[e] = (short)f2bf(wr[e]);
            acc[nt] = mfma16(a, b, acc[nt]);
        }
    }
    #pragma unroll
    for (int nt = 0; nt < 4; ++nt) {
        int ncol = wave * 64 + nt * 16 + col_l;
        float bias = b3[ncol];
        #pragma unroll
        for (int i = 0; i < 4; ++i) {
            float v = acc[nt][i] + bias;
            out2[quad * 4 + i][ncol] = v > 0.f ? v : 0.f;
        }
    }
    __syncthreads();
    // per-cultivar head: 16 batches x 16 outputs = 256 threads, 256-MAC dot each
    int b_local = tid >> 4, o2 = tid & 15;
    int batch = bbase + b_local;
    int c = cult[batch];
    float acc2 = bh[c * 16 + o2];
    const float* wrow = Wh + (size_t)(c * 16 + o2) * 256;
    for (int d = 0; d < 256; ++d) acc2 += out2[b_local][d] * wrow[d];
    params[(size_t)batch * 16 + o2] = acc2;
}

// ---------------- launcher ----------------
extern "C" void kernel_launch(void* const* d_in, const int* in_sizes, int n_in,
                              void* d_out, int out_size, void* d_ws, size_t ws_size,
                              hipStream_t stream) {
    (void)in_sizes; (void)n_in; (void)out_size; (void)ws_size;
    const float* input = (const float*)d_in[0];
    const float* hn    = (const float*)d_in[1];
    const int*   cult  = (const int*)d_in[2];
    const float* W1    = (const float*)d_in[3];
    const float* b1    = (const float*)d_in[4];
    const float* W2    = (const float*)d_in[5];
    const float* b2    = (const float*)d_in[6];
    const float* W_ih  = (const float*)d_in[7];
    const float* W_hh  = (const float*)d_in[8];
    const float* b_ih  = (const float*)d_in[9];
    const float* b_hh  = (const float*)d_in[10];
    const float* W3    = (const float*)d_in[11];
    const float* b3    = (const float*)d_in[12];
    const float* Wh    = (const float*)d_in[13];
    const float* bh    = (const float*)d_in[14];

    char* ws = (char*)d_ws;
    u16*      hbuf0 = (u16*)(ws + WS_HBUF0);
    u16*      hbuf1 = (u16*)(ws + WS_HBUF1);
    float*    W21   = (float*)(ws + WS_W21);
    float*    b21   = (float*)(ws + WS_B21);
    u16*      Weff  = (u16*)(ws + WS_WEFF);
    float*    beff  = (float*)(ws + WS_BEFF);
    unsigned* flags = (unsigned*)(ws + WS_FLAGS);

    float* out    = (float*)d_out;
    float* params = out;            // 1024*16 fp32
    float* hnout  = out + 16384;    // 1024*512 fp32

    k_prep0<<<64, 256, 0, stream>>>(W1, b1, W2, b2, W21, b21, flags);
    k_prep1<<<192, 256, 0, stream>>>(W_ih, b_ih, W21, b21, Weff, beff);
    k_gru<<<512, 256, 0, stream>>>(input, hn, W_hh, b_hh, Weff, beff,
                                   hbuf0, hbuf1, flags, hnout);
    k_head<<<64, 256, 0, stream>>>(hbuf0, W3, b3, cult, Wh, bh, params);
}